// Round 5
// baseline (180.580 us; speedup 1.0000x reference)
//
#include <hip/hip_runtime.h>
#include <hip/hip_bf16.h>
#include <stdint.h>
#include <stddef.h>

#define TT 4096
#define CC 1024
#define NFD 1024
#define N3 3072

typedef __bf16 bf16;
typedef __bf16 bf16x8 __attribute__((ext_vector_type(8)));
typedef __bf16 bf16x4 __attribute__((ext_vector_type(4)));
typedef float f32x4 __attribute__((ext_vector_type(4)));

typedef const __attribute__((address_space(1))) unsigned char gl_u8;
typedef __attribute__((address_space(3))) unsigned char lds_u8;

__device__ __forceinline__ void glds16(const void* g, void* l) {
  __builtin_amdgcn_global_load_lds((gl_u8*)g, (lds_u8*)l, 16, 0, 0);
}

// ---------- 4-wave (256-thread) core: 128x128 tile, BK=32 ----------
__device__ __forceinline__ void stage128x32(const bf16* __restrict__ src, int ld, bf16* lds, int tid) {
  const int lane = tid & 63;
  const int w = tid >> 6;
#pragma unroll
  for (int p = 0; p < 2; ++p) {
    const int lbyte = w * 2048 + p * 1024;              // wave-uniform LDS base (bytes)
    const int row = (lbyte >> 6) + (lane >> 2);         // this lane's 16B lands at row, k8
    const int kel = (lane & 3) << 3;
    glds16(src + row * ld + kel, (char*)lds + lbyte);
  }
}

__device__ __forceinline__ void gemm_core(const bf16* __restrict__ A, const bf16* __restrict__ B,
                                          int lda, int ldb, int ksteps,
                                          bf16* As, bf16* Bs, int tid, f32x4 (&acc)[4][4]) {
  const int lane = tid & 63;
  const int w = tid >> 6;
  const int wm = (w >> 1) * 64;
  const int wn = (w & 1) * 64;
  const int lrow = lane & 15;
  const int lko = (lane >> 4) * 8;
  stage128x32(A, lda, As, tid);
  stage128x32(B, ldb, Bs, tid);
  __syncthreads();
  for (int ks = 0; ks < ksteps; ++ks) {
    const bf16* Ac = As + (ks & 1) * 4096;
    const bf16* Bc = Bs + (ks & 1) * 4096;
    if (ks + 1 < ksteps) {
      stage128x32(A + (ks + 1) * 32, lda, As + ((ks + 1) & 1) * 4096, tid);
      stage128x32(B + (ks + 1) * 32, ldb, Bs + ((ks + 1) & 1) * 4096, tid);
    }
    bf16x8 af[4], bfr[4];
#pragma unroll
    for (int i = 0; i < 4; ++i)
      af[i] = *(const bf16x8*)(Ac + (wm + i * 16 + lrow) * 32 + lko);
#pragma unroll
    for (int i = 0; i < 4; ++i)
      bfr[i] = *(const bf16x8*)(Bc + (wn + i * 16 + lrow) * 32 + lko);
#pragma unroll
    for (int mi = 0; mi < 4; ++mi)
#pragma unroll
      for (int ni = 0; ni < 4; ++ni)
        acc[mi][ni] = __builtin_amdgcn_mfma_f32_16x16x32_bf16(af[mi], bfr[ni], acc[mi][ni], 0, 0, 0);
    __syncthreads();
  }
}

// ---------- 8-wave (512-thread) core: 256x128 tile, BK=32 ----------
__device__ __forceinline__ void stageA256(const bf16* __restrict__ src, int ld, bf16* lds, int tid) {
  const int lane = tid & 63;
  const int w = tid >> 6;  // 0..7
#pragma unroll
  for (int p = 0; p < 2; ++p) {
    const int lbyte = w * 2048 + p * 1024;              // 16 KB total
    const int row = (lbyte >> 6) + (lane >> 2);         // 0..255
    const int kel = (lane & 3) << 3;
    glds16(src + row * ld + kel, (char*)lds + lbyte);
  }
}
__device__ __forceinline__ void stageB128_8w(const bf16* __restrict__ src, int ld, bf16* lds, int tid) {
  const int lane = tid & 63;
  const int w = tid >> 6;  // 0..7
  const int lbyte = w * 1024;                           // 8 KB total
  const int row = (lbyte >> 6) + (lane >> 2);           // 0..127
  const int kel = (lane & 3) << 3;
  glds16(src + row * ld + kel, (char*)lds + lbyte);
}

// 8 waves as 4(M) x 2(N) of 64x64. As: 2*256*32, Bs: 2*128*32 elements.
__device__ __forceinline__ void gemm_core_256(const bf16* __restrict__ A, const bf16* __restrict__ B,
                                              int lda, int ldb, int ksteps,
                                              bf16* As, bf16* Bs, int tid, f32x4 (&acc)[4][4]) {
  const int lane = tid & 63;
  const int w = tid >> 6;
  const int wm = (w >> 1) * 64;   // 0..192
  const int wn = (w & 1) * 64;    // 0,64
  const int lrow = lane & 15;
  const int lko = (lane >> 4) * 8;
  stageA256(A, lda, As, tid);
  stageB128_8w(B, ldb, Bs, tid);
  __syncthreads();
  for (int ks = 0; ks < ksteps; ++ks) {
    const bf16* Ac = As + (ks & 1) * 8192;
    const bf16* Bc = Bs + (ks & 1) * 4096;
    if (ks + 1 < ksteps) {
      stageA256(A + (ks + 1) * 32, lda, As + ((ks + 1) & 1) * 8192, tid);
      stageB128_8w(B + (ks + 1) * 32, ldb, Bs + ((ks + 1) & 1) * 4096, tid);
    }
    bf16x8 af[4], bfr[4];
#pragma unroll
    for (int i = 0; i < 4; ++i)
      af[i] = *(const bf16x8*)(Ac + (wm + i * 16 + lrow) * 32 + lko);
#pragma unroll
    for (int i = 0; i < 4; ++i)
      bfr[i] = *(const bf16x8*)(Bc + (wn + i * 16 + lrow) * 32 + lko);
#pragma unroll
    for (int mi = 0; mi < 4; ++mi)
#pragma unroll
      for (int ni = 0; ni < 4; ++ni)
        acc[mi][ni] = __builtin_amdgcn_mfma_f32_16x16x32_bf16(af[mi], bfr[ni], acc[mi][ni], 0, 0, 0);
    __syncthreads();
  }
}

// ---- K0: merged prep. blocks [0,2048): x fp32->bf16. blocks [2048,2816): W transpose. ----
__global__ __launch_bounds__(256) void k_prep(const float* __restrict__ x, bf16* __restrict__ xb,
                                              const float* __restrict__ Wsrc, bf16* __restrict__ WbT) {
  __shared__ float Ls[64][68];
  const int tid = threadIdx.x;
  if (blockIdx.x < 2048) {
    int idx = (blockIdx.x * 256 + tid) * 8;
    f32x4 a = *(const f32x4*)(x + idx);
    f32x4 b = *(const f32x4*)(x + idx + 4);
    bf16x8 o;
#pragma unroll
    for (int j = 0; j < 4; ++j) { o[j] = (bf16)a[j]; o[4 + j] = (bf16)b[j]; }
    *(bf16x8*)(xb + idx) = o;
    return;
  }
  const int bid = blockIdx.x - 2048;
  const int n0 = (bid % 48) * 64;
  const int c0 = (bid / 48) * 64;
#pragma unroll
  for (int qq = 0; qq < 4; ++qq) {
    int lin = qq * 1024 + tid * 4;
    int r = lin >> 6, cc = lin & 63;
    f32x4 v = *(const f32x4*)(Wsrc + (size_t)(c0 + r) * N3 + n0 + cc);
#pragma unroll
    for (int j = 0; j < 4; ++j) Ls[r][cc + j] = v[j];
  }
  __syncthreads();
#pragma unroll
  for (int qq = 0; qq < 4; ++qq) {
    int lin = qq * 1024 + tid * 4;
    int nr = lin >> 6, cc = lin & 63;
    bf16x4 o;
#pragma unroll
    for (int j = 0; j < 4; ++j) o[j] = (bf16)Ls[cc + j][nr];
    *(bf16x4*)(WbT + (size_t)(n0 + nr) * CC + c0 + cc) = o;
  }
}

// ---- K1: qkv = xb @ WbT^T + b ; writes q,k natural [t][c] and v transposed [d][t] ----
__global__ __launch_bounds__(256, 2) void k_qkv(const bf16* __restrict__ xb, const bf16* __restrict__ wbt,
                                                const float* __restrict__ bias,
                                                bf16* __restrict__ q, bf16* __restrict__ k,
                                                bf16* __restrict__ vT) {
  __shared__ bf16 As[2 * 128 * 32], Bs[2 * 128 * 32];
  const int tid = threadIdx.x;
  const int m0 = blockIdx.y * 128;
  const int n0 = blockIdx.x * 128;
  f32x4 acc[4][4];
#pragma unroll
  for (int i = 0; i < 4; ++i)
#pragma unroll
    for (int j = 0; j < 4; ++j) acc[i][j] = (f32x4){0.f, 0.f, 0.f, 0.f};

  gemm_core(xb + (size_t)m0 * CC, wbt + (size_t)n0 * CC, CC, CC, CC / 32, As, Bs, tid, acc);

  const int lane = tid & 63;
  const int w = tid >> 6;
  const int wm = (w >> 1) * 64, wn = (w & 1) * 64;
  const int seg = n0 >> 10;  // 0:q 1:k 2:v
#pragma unroll
  for (int mi = 0; mi < 4; ++mi) {
    const int tB = m0 + wm + mi * 16 + ((lane >> 4) << 2);
#pragma unroll
    for (int ni = 0; ni < 4; ++ni) {
      const int n = n0 + wn + ni * 16 + (lane & 15);
      const float bb = bias[n];
      f32x4 a = acc[mi][ni];
      if (seg == 2) {
        bf16x4 pv;
#pragma unroll
        for (int r = 0; r < 4; ++r) pv[r] = (bf16)(a[r] + bb);
        *(bf16x4*)(vT + (size_t)(n - 2048) * TT + tB) = pv;  // vT[d][t]
      } else {
        bf16* dst = (seg == 0) ? q : k;
        const int nl = n & 1023;
#pragma unroll
        for (int r = 0; r < 4; ++r) dst[(size_t)(tB + r) * NFD + nl] = (bf16)(a[r] + bb);
      }
    }
  }
}

// ---- K2: P' = exp(mask(q @ k^T / 32)) as bf16; row sums l via atomicAdd.
//      Also zero-fills above-diagonal tiles (it, it+1) for even it — these are
//      read by k_pvc's 256-row stripes (upper half) and otherwise hold garbage. ----
__global__ __launch_bounds__(256, 2) void k_scores(const bf16* __restrict__ q, const bf16* __restrict__ kk,
                                                   bf16* __restrict__ P, float* __restrict__ l,
                                                   const int* __restrict__ npadd_p) {
  const int jt = blockIdx.x, it = blockIdx.y;
  const int np = *npadd_p;
  const int jt0 = np >> 7;
  if (jt == it + 1 && (it & 1) == 0) {
    // zero-fill this never-computed tile so k_pvc's stripe read is clean
    bf16x8 z;
#pragma unroll
    for (int j = 0; j < 8; ++j) z[j] = (bf16)0.f;
    for (int t = threadIdx.x; t < 128 * 16; t += 256) {
      const int r = t >> 4, cs = t & 15;
      *(bf16x8*)(P + (size_t)(it * 128 + r) * TT + jt * 128 + cs * 8) = z;
    }
    return;
  }
  if (jt > it || jt < jt0) return;  // fully-masked tile: never read by K3
  __shared__ bf16 As[2 * 128 * 32], Bs[2 * 128 * 32];
  const int tid = threadIdx.x;
  f32x4 acc[4][4];
#pragma unroll
  for (int i = 0; i < 4; ++i)
#pragma unroll
    for (int j = 0; j < 4; ++j) acc[i][j] = (f32x4){0.f, 0.f, 0.f, 0.f};

  gemm_core(q + (size_t)it * 128 * CC, kk + (size_t)jt * 128 * CC, CC, CC, CC / 32, As, Bs, tid, acc);

  const int lane = tid & 63;
  const int w = tid >> 6;
  const int wm = (w >> 1) * 64, wn = (w & 1) * 64;
  const float scale = 0.03125f;  // 1/sqrt(1024)
#pragma unroll
  for (int mi = 0; mi < 4; ++mi) {
    const int iB = it * 128 + wm + mi * 16 + ((lane >> 4) << 2);
    float rs[4] = {0.f, 0.f, 0.f, 0.f};
#pragma unroll
    for (int ni = 0; ni < 4; ++ni) {
      const int j = jt * 128 + wn + ni * 16 + (lane & 15);
      f32x4 a = acc[mi][ni];
#pragma unroll
      for (int r = 0; r < 4; ++r) {
        const int i = iB + r;
        float p = 0.f;
        if (j <= i && j >= np && i >= np) p = __expf(a[r] * scale);
        const bf16 pb = (bf16)p;
        P[(size_t)i * TT + j] = pb;
        rs[r] += (float)pb;
      }
    }
#pragma unroll
    for (int r = 0; r < 4; ++r) {
      float v = rs[r];
      v += __shfl_xor(v, 1);
      v += __shfl_xor(v, 2);
      v += __shfl_xor(v, 4);
      v += __shfl_xor(v, 8);
      if ((lane & 15) == 0) atomicAdd(&l[iB + r], v);
    }
  }
}

// ---- K3a: split-K PV, 256x128 tile, 8 waves. chunk c covers j-tiles [4c, 4c+4). ----
__global__ __launch_bounds__(512, 4) void k_pvc(const bf16* __restrict__ P, const bf16* __restrict__ vT,
                                                float* __restrict__ yacc,
                                                const int* __restrict__ npadd_p) {
  const int c = blockIdx.x;       // 0..7
  const int it = blockIdx.y;      // 0..15 (256-row tiles)
  const int d0 = blockIdx.z * 128;
  const int np = *npadd_p;
  const int jt0 = np >> 7;
  const int jmax = 2 * it + 2;    // exclusive 128-wide j-tile bound for this row stripe
  int jlo = 4 * c; if (jlo < jt0) jlo = jt0;
  int jhi = 4 * c + 4; if (jhi > jmax) jhi = jmax;
  if (jlo >= jhi) return;

  __shared__ bf16 As[2 * 256 * 32], Bs[2 * 128 * 32];
  const int tid = threadIdx.x;
  f32x4 acc[4][4];
#pragma unroll
  for (int i = 0; i < 4; ++i)
#pragma unroll
    for (int j = 0; j < 4; ++j) acc[i][j] = (f32x4){0.f, 0.f, 0.f, 0.f};

  gemm_core_256(P + (size_t)it * 256 * TT + (size_t)jlo * 128,
                vT + (size_t)d0 * TT + (size_t)jlo * 128,
                TT, TT, (jhi - jlo) * 4, As, Bs, tid, acc);

  const int lane = tid & 63;
  const int w = tid >> 6;
  const int wm = (w >> 1) * 64, wn = (w & 1) * 64;
  // sole-writer tile? (chunk covers this stripe's entire valid j range)
  const bool full = (4 * c <= jt0) && (4 * c + 4 >= jmax);
#pragma unroll
  for (int mi = 0; mi < 4; ++mi) {
    const int iB = it * 256 + wm + mi * 16 + ((lane >> 4) << 2);
#pragma unroll
    for (int ni = 0; ni < 4; ++ni) {
      const int d = d0 + wn + ni * 16 + (lane & 15);
      f32x4 a = acc[mi][ni];
#pragma unroll
      for (int r = 0; r < 4; ++r) {
        float* p = &yacc[(size_t)(iB + r) * NFD + d];
        if (full) *p = a[r];
        else atomicAdd(p, a[r]);
      }
    }
  }
}

// ---- K3b: y = yacc / l for i>=np else 0 ----
__global__ __launch_bounds__(256) void k_norm(const float* __restrict__ yacc, const float* __restrict__ l,
                                              float* __restrict__ y, const int* __restrict__ npadd_p) {
  const int idx = (blockIdx.x * 256 + threadIdx.x) * 4;
  const int i = idx >> 10;  // / NFD
  const int np = *npadd_p;
  f32x4 v = (f32x4){0.f, 0.f, 0.f, 0.f};
  if (i >= np) {
    f32x4 a = *(const f32x4*)(yacc + idx);
    const float inv = 1.0f / l[i];
#pragma unroll
    for (int j = 0; j < 4; ++j) v[j] = a[j] * inv;
  }
  *(f32x4*)(y + idx) = v;
}

extern "C" void kernel_launch(void* const* d_in, const int* in_sizes, int n_in,
                              void* d_out, int out_size, void* d_ws, size_t ws_size,
                              hipStream_t stream) {
  const float* x = (const float*)d_in[0];
  const float* W = (const float*)d_in[1];
  const float* b = (const float*)d_in[2];
  const int* npadd = (const int*)d_in[3];
  float* y = (float*)d_out;

  char* ws = (char*)d_ws;
  const size_t MB = 1u << 20;
  bf16* q  = (bf16*)(ws + 0 * MB);          // 8 MB  [T][C]   (dead after k_scores)
  bf16* kk = (bf16*)(ws + 8 * MB);          // 8 MB  [T][C]   (dead after k_scores)
  float* yacc = (float*)(ws + 0 * MB);      // 16 MB [T][D] fp32, overlays q+kk
  bf16* vT = (bf16*)(ws + 16 * MB);         // 8 MB  [D][T]
  float* l = (float*)(ws + 24 * MB);        // 16 KB
  bf16* P  = (bf16*)(ws + 24 * MB + 65536); // 32 MB [T][T]
  bf16* xb = P;                              // overlap: dead before K2 writes P
  bf16* WbT = (bf16*)((char*)P + 8 * MB);    // 6 MB, also dead before K2

  // K0: convert x + transpose/convert W (merged, independent regions)
  k_prep<<<dim3(2048 + 768), 256, 0, stream>>>(x, xb, W, WbT);
  // K1: QKV projection
  k_qkv<<<dim3(N3 / 128, TT / 128), 256, 0, stream>>>(xb, WbT, b, q, kk, vT);
  // K2: masked exp-scores + row sums (+ zero-fill of even above-diagonal tiles)
  hipMemsetAsync(l, 0, TT * sizeof(float), stream);
  k_scores<<<dim3(TT / 128, TT / 128), 256, 0, stream>>>(q, kk, P, l, npadd);
  // K3: split-K PV, 256x128 tiles, chunks of 4 j-tiles (K=512)
  hipMemsetAsync(yacc, 0, (size_t)TT * NFD * sizeof(float), stream);
  k_pvc<<<dim3(8, TT / 256, NFD / 128), 512, 0, stream>>>(P, vT, yacc, npadd);
  // K3b: normalize
  k_norm<<<dim3((TT * NFD) / (256 * 4)), 256, 0, stream>>>(yacc, l, y, npadd);
}

// Round 6
// 132.869 us; speedup vs baseline: 1.3591x; 1.3591x over previous
//
#include <hip/hip_runtime.h>
#include <hip/hip_bf16.h>
#include <stdint.h>
#include <stddef.h>

#define TT 4096
#define CC 1024
#define NFD 1024
#define N3 3072
#define JSPLIT 17  // j-tile chunk boundary for split-K PV (balances both chunks at <=60 K-steps)

typedef __bf16 bf16;
typedef __bf16 bf16x8 __attribute__((ext_vector_type(8)));
typedef __bf16 bf16x4 __attribute__((ext_vector_type(4)));
typedef float f32x4 __attribute__((ext_vector_type(4)));

typedef const __attribute__((address_space(1))) unsigned char gl_u8;
typedef __attribute__((address_space(3))) unsigned char lds_u8;

__device__ __forceinline__ void glds16(const void* g, void* l) {
  __builtin_amdgcn_global_load_lds((gl_u8*)g, (lds_u8*)l, 16, 0, 0);
}

// ---------- 4-wave (256-thread) core: 128x128 tile, BK=32 ----------
__device__ __forceinline__ void stage128x32(const bf16* __restrict__ src, int ld, bf16* lds, int tid) {
  const int lane = tid & 63;
  const int w = tid >> 6;
#pragma unroll
  for (int p = 0; p < 2; ++p) {
    const int lbyte = w * 2048 + p * 1024;              // wave-uniform LDS base (bytes)
    const int row = (lbyte >> 6) + (lane >> 2);         // this lane's 16B lands at row, k8
    const int kel = (lane & 3) << 3;
    glds16(src + row * ld + kel, (char*)lds + lbyte);
  }
}

__device__ __forceinline__ void gemm_core(const bf16* __restrict__ A, const bf16* __restrict__ B,
                                          int lda, int ldb, int ksteps,
                                          bf16* As, bf16* Bs, int tid, f32x4 (&acc)[4][4]) {
  const int lane = tid & 63;
  const int w = tid >> 6;
  const int wm = (w >> 1) * 64;
  const int wn = (w & 1) * 64;
  const int lrow = lane & 15;
  const int lko = (lane >> 4) * 8;
  stage128x32(A, lda, As, tid);
  stage128x32(B, ldb, Bs, tid);
  __syncthreads();
  for (int ks = 0; ks < ksteps; ++ks) {
    const bf16* Ac = As + (ks & 1) * 4096;
    const bf16* Bc = Bs + (ks & 1) * 4096;
    if (ks + 1 < ksteps) {
      stage128x32(A + (ks + 1) * 32, lda, As + ((ks + 1) & 1) * 4096, tid);
      stage128x32(B + (ks + 1) * 32, ldb, Bs + ((ks + 1) & 1) * 4096, tid);
    }
    bf16x8 af[4], bfr[4];
#pragma unroll
    for (int i = 0; i < 4; ++i)
      af[i] = *(const bf16x8*)(Ac + (wm + i * 16 + lrow) * 32 + lko);
#pragma unroll
    for (int i = 0; i < 4; ++i)
      bfr[i] = *(const bf16x8*)(Bc + (wn + i * 16 + lrow) * 32 + lko);
#pragma unroll
    for (int mi = 0; mi < 4; ++mi)
#pragma unroll
      for (int ni = 0; ni < 4; ++ni)
        acc[mi][ni] = __builtin_amdgcn_mfma_f32_16x16x32_bf16(af[mi], bfr[ni], acc[mi][ni], 0, 0, 0);
    __syncthreads();
  }
}

// ---- K0: merged prep. blocks [0,2048): x fp32->bf16. blocks [2048,2816): W transpose. ----
__global__ __launch_bounds__(256) void k_prep(const float* __restrict__ x, bf16* __restrict__ xb,
                                              const float* __restrict__ Wsrc, bf16* __restrict__ WbT) {
  __shared__ float Ls[64][68];
  const int tid = threadIdx.x;
  if (blockIdx.x < 2048) {
    int idx = (blockIdx.x * 256 + tid) * 8;
    f32x4 a = *(const f32x4*)(x + idx);
    f32x4 b = *(const f32x4*)(x + idx + 4);
    bf16x8 o;
#pragma unroll
    for (int j = 0; j < 4; ++j) { o[j] = (bf16)a[j]; o[4 + j] = (bf16)b[j]; }
    *(bf16x8*)(xb + idx) = o;
    return;
  }
  const int bid = blockIdx.x - 2048;
  const int n0 = (bid % 48) * 64;
  const int c0 = (bid / 48) * 64;
#pragma unroll
  for (int qq = 0; qq < 4; ++qq) {
    int lin = qq * 1024 + tid * 4;
    int r = lin >> 6, cc = lin & 63;
    f32x4 v = *(const f32x4*)(Wsrc + (size_t)(c0 + r) * N3 + n0 + cc);
#pragma unroll
    for (int j = 0; j < 4; ++j) Ls[r][cc + j] = v[j];
  }
  __syncthreads();
#pragma unroll
  for (int qq = 0; qq < 4; ++qq) {
    int lin = qq * 1024 + tid * 4;
    int nr = lin >> 6, cc = lin & 63;
    bf16x4 o;
#pragma unroll
    for (int j = 0; j < 4; ++j) o[j] = (bf16)Ls[cc + j][nr];
    *(bf16x4*)(WbT + (size_t)(n0 + nr) * CC + c0 + cc) = o;
  }
}

// ---- K1: qkv = xb @ WbT^T + b ; writes q,k natural [t][c] and v transposed [d][t] ----
__global__ __launch_bounds__(256, 2) void k_qkv(const bf16* __restrict__ xb, const bf16* __restrict__ wbt,
                                                const float* __restrict__ bias,
                                                bf16* __restrict__ q, bf16* __restrict__ k,
                                                bf16* __restrict__ vT) {
  __shared__ bf16 As[2 * 128 * 32], Bs[2 * 128 * 32];
  const int tid = threadIdx.x;
  const int m0 = blockIdx.y * 128;
  const int n0 = blockIdx.x * 128;
  f32x4 acc[4][4];
#pragma unroll
  for (int i = 0; i < 4; ++i)
#pragma unroll
    for (int j = 0; j < 4; ++j) acc[i][j] = (f32x4){0.f, 0.f, 0.f, 0.f};

  gemm_core(xb + (size_t)m0 * CC, wbt + (size_t)n0 * CC, CC, CC, CC / 32, As, Bs, tid, acc);

  const int lane = tid & 63;
  const int w = tid >> 6;
  const int wm = (w >> 1) * 64, wn = (w & 1) * 64;
  const int seg = n0 >> 10;  // 0:q 1:k 2:v
#pragma unroll
  for (int mi = 0; mi < 4; ++mi) {
    const int tB = m0 + wm + mi * 16 + ((lane >> 4) << 2);
#pragma unroll
    for (int ni = 0; ni < 4; ++ni) {
      const int n = n0 + wn + ni * 16 + (lane & 15);
      const float bb = bias[n];
      f32x4 a = acc[mi][ni];
      if (seg == 2) {
        bf16x4 pv;
#pragma unroll
        for (int r = 0; r < 4; ++r) pv[r] = (bf16)(a[r] + bb);
        *(bf16x4*)(vT + (size_t)(n - 2048) * TT + tB) = pv;  // vT[d][t]
      } else {
        bf16* dst = (seg == 0) ? q : k;
        const int nl = n & 1023;
#pragma unroll
        for (int r = 0; r < 4; ++r) dst[(size_t)(tB + r) * NFD + nl] = (bf16)(a[r] + bb);
      }
    }
  }
}

// ---- K2: P' = exp(mask(q @ k^T / 32)) as bf16; row sums l via atomicAdd ----
__global__ __launch_bounds__(256, 2) void k_scores(const bf16* __restrict__ q, const bf16* __restrict__ kk,
                                                   bf16* __restrict__ P, float* __restrict__ l,
                                                   const int* __restrict__ npadd_p) {
  const int jt = blockIdx.x, it = blockIdx.y;
  const int np = *npadd_p;
  const int jt0 = np >> 7;
  if (jt > it || jt < jt0) return;  // fully-masked tile: never read by K3
  __shared__ bf16 As[2 * 128 * 32], Bs[2 * 128 * 32];
  const int tid = threadIdx.x;
  f32x4 acc[4][4];
#pragma unroll
  for (int i = 0; i < 4; ++i)
#pragma unroll
    for (int j = 0; j < 4; ++j) acc[i][j] = (f32x4){0.f, 0.f, 0.f, 0.f};

  gemm_core(q + (size_t)it * 128 * CC, kk + (size_t)jt * 128 * CC, CC, CC, CC / 32, As, Bs, tid, acc);

  const int lane = tid & 63;
  const int w = tid >> 6;
  const int wm = (w >> 1) * 64, wn = (w & 1) * 64;
  const float scale = 0.03125f;  // 1/sqrt(1024)
#pragma unroll
  for (int mi = 0; mi < 4; ++mi) {
    const int iB = it * 128 + wm + mi * 16 + ((lane >> 4) << 2);
    float rs[4] = {0.f, 0.f, 0.f, 0.f};
#pragma unroll
    for (int ni = 0; ni < 4; ++ni) {
      const int j = jt * 128 + wn + ni * 16 + (lane & 15);
      f32x4 a = acc[mi][ni];
#pragma unroll
      for (int r = 0; r < 4; ++r) {
        const int i = iB + r;
        float p = 0.f;
        if (j <= i && j >= np && i >= np) p = __expf(a[r] * scale);
        const bf16 pb = (bf16)p;
        P[(size_t)i * TT + j] = pb;
        rs[r] += (float)pb;
      }
    }
#pragma unroll
    for (int r = 0; r < 4; ++r) {
      float v = rs[r];
      v += __shfl_xor(v, 1);
      v += __shfl_xor(v, 2);
      v += __shfl_xor(v, 4);
      v += __shfl_xor(v, 8);
      if ((lane & 15) == 0) atomicAdd(&l[iB + r], v);
    }
  }
}

// ---- K3a: 2-way split-K PV, NO atomics. chunk 0: j-tiles [jt0, 17); chunk 1: [17, it+1).
//      Each chunk writes its own bf16 partial buffer with plain stores. ----
__global__ __launch_bounds__(256, 2) void k_pvc(const bf16* __restrict__ P, const bf16* __restrict__ vT,
                                                bf16* __restrict__ part0, bf16* __restrict__ part1,
                                                const int* __restrict__ npadd_p) {
  const int c = blockIdx.x;       // 0..1
  const int it = blockIdx.y;      // 0..31
  const int d0 = blockIdx.z * 128;
  const int np = *npadd_p;
  const int jt0 = np >> 7;
  int jlo, jhi;
  if (c == 0) { jlo = jt0;                      jhi = min(JSPLIT, it + 1); }
  else        { jlo = max(JSPLIT, jt0);         jhi = it + 1; }
  if (jlo >= jhi) return;

  __shared__ bf16 As[2 * 128 * 32], Bs[2 * 128 * 32];
  const int tid = threadIdx.x;
  f32x4 acc[4][4];
#pragma unroll
  for (int i = 0; i < 4; ++i)
#pragma unroll
    for (int j = 0; j < 4; ++j) acc[i][j] = (f32x4){0.f, 0.f, 0.f, 0.f};

  gemm_core(P + (size_t)it * 128 * TT + (size_t)jlo * 128,
            vT + (size_t)d0 * TT + (size_t)jlo * 128,
            TT, TT, (jhi - jlo) * 4, As, Bs, tid, acc);

  bf16* __restrict__ part = (c == 0) ? part0 : part1;
  const int lane = tid & 63;
  const int w = tid >> 6;
  const int wm = (w >> 1) * 64, wn = (w & 1) * 64;
#pragma unroll
  for (int mi = 0; mi < 4; ++mi) {
    const int iB = it * 128 + wm + mi * 16 + ((lane >> 4) << 2);
#pragma unroll
    for (int ni = 0; ni < 4; ++ni) {
      const int d = d0 + wn + ni * 16 + (lane & 15);
      f32x4 a = acc[mi][ni];
#pragma unroll
      for (int r = 0; r < 4; ++r)
        part[(size_t)(iB + r) * NFD + d] = (bf16)a[r];
    }
  }
}

// ---- K3b: y = (part0 [+ part1]) / l for i>=np else 0 ----
__global__ __launch_bounds__(256) void k_norm(const bf16* __restrict__ part0, const bf16* __restrict__ part1,
                                              const float* __restrict__ l, float* __restrict__ y,
                                              const int* __restrict__ npadd_p) {
  const int idx = (blockIdx.x * 256 + threadIdx.x) * 8;
  const int i = idx >> 10;  // / NFD
  const int np = *npadd_p;
  const int jt0 = np >> 7;
  const int it = i >> 7;
  float s[8] = {0.f, 0.f, 0.f, 0.f, 0.f, 0.f, 0.f, 0.f};
  float inv = 0.f;
  if (i >= np) {
    inv = 1.0f / l[i];
    if (min(JSPLIT, it + 1) > jt0) {          // chunk-0 partial exists for this row
      bf16x8 a = *(const bf16x8*)(part0 + idx);
#pragma unroll
      for (int j = 0; j < 8; ++j) s[j] += (float)a[j];
    }
    if (it + 1 > max(JSPLIT, jt0)) {          // chunk-1 partial exists for this row
      bf16x8 b = *(const bf16x8*)(part1 + idx);
#pragma unroll
      for (int j = 0; j < 8; ++j) s[j] += (float)b[j];
    }
  }
  f32x4 o0, o1;
#pragma unroll
  for (int j = 0; j < 4; ++j) { o0[j] = s[j] * inv; o1[j] = s[4 + j] * inv; }
  *(f32x4*)(y + idx) = o0;
  *(f32x4*)(y + idx + 4) = o1;
}

extern "C" void kernel_launch(void* const* d_in, const int* in_sizes, int n_in,
                              void* d_out, int out_size, void* d_ws, size_t ws_size,
                              hipStream_t stream) {
  const float* x = (const float*)d_in[0];
  const float* W = (const float*)d_in[1];
  const float* b = (const float*)d_in[2];
  const int* npadd = (const int*)d_in[3];
  float* y = (float*)d_out;

  char* ws = (char*)d_ws;
  const size_t MB = 1u << 20;
  bf16* q  = (bf16*)(ws + 0 * MB);          // 8 MB  [T][C]   (dead after k_scores)
  bf16* kk = (bf16*)(ws + 8 * MB);          // 8 MB  [T][C]   (dead after k_scores)
  bf16* part0 = (bf16*)(ws + 0 * MB);       // 8 MB [T][D] bf16, overlays q
  bf16* part1 = (bf16*)(ws + 8 * MB);       // 8 MB [T][D] bf16, overlays kk
  bf16* vT = (bf16*)(ws + 16 * MB);         // 8 MB  [D][T]
  float* l = (float*)(ws + 24 * MB);        // 16 KB
  bf16* P  = (bf16*)(ws + 24 * MB + 65536); // 32 MB [T][T]
  bf16* xb = P;                              // overlap: dead before K2 writes P
  bf16* WbT = (bf16*)((char*)P + 8 * MB);    // 6 MB, also dead before K2

  // K0: convert x + transpose/convert W (merged, independent regions)
  k_prep<<<dim3(2048 + 768), 256, 0, stream>>>(x, xb, W, WbT);
  // K1: QKV projection
  k_qkv<<<dim3(N3 / 128, TT / 128), 256, 0, stream>>>(xb, WbT, b, q, kk, vT);
  // K2: masked exp-scores + row sums
  hipMemsetAsync(l, 0, TT * sizeof(float), stream);
  k_scores<<<dim3(TT / 128, TT / 128), 256, 0, stream>>>(q, kk, P, l, npadd);
  // K3: 2-way split-K PV into bf16 partials (no atomics, no accumulator memset)
  k_pvc<<<dim3(2, TT / 128, NFD / 128), 256, 0, stream>>>(P, vT, part0, part1, npadd);
  // K3b: sum partials + normalize
  k_norm<<<dim3((TT * NFD) / (256 * 8)), 256, 0, stream>>>(part0, part1, l, y, npadd);
}